// Round 1
// baseline (800.604 us; speedup 1.0000x reference)
//
#include <hip/hip_runtime.h>
#include <hip/hip_bf16.h>
#include <stdint.h>

#define BATCH 4
#define SEQ   4096          // 64*64 spatial
#define CH    512
#define NGRP  32
#define GEPS  1e-6f

typedef short  short8  __attribute__((ext_vector_type(8)));
typedef float  floatx4 __attribute__((ext_vector_type(4)));

static __device__ __forceinline__ short bf16b(float f) {
    __hip_bfloat16 h = __float2bfloat16(f);
    return __builtin_bit_cast(short, h);
}

// ---------------- GroupNorm: stats per (b, g) over SEQ x 16 channels ----------------
__global__ __launch_bounds__(256) void gn_stats_kernel(const float* __restrict__ x,
                                                       float* __restrict__ stats) {
    int bg = blockIdx.x;            // 0..127
    int b = bg >> 5, g = bg & 31;
    int t = threadIdx.x;
    const float* base = x + (size_t)b * SEQ * CH + g * 16;
    float s1 = 0.f, s2 = 0.f;
    #pragma unroll 4
    for (int i = 0; i < 256; ++i) {
        int idx = i * 256 + t;          // 65536 elems
        int l = idx >> 4, c = idx & 15;
        float v = base[(size_t)l * CH + c];
        s1 += v; s2 += v * v;
    }
    __shared__ float r1[256], r2[256];
    r1[t] = s1; r2[t] = s2;
    __syncthreads();
    for (int off = 128; off > 0; off >>= 1) {
        if (t < off) { r1[t] += r1[t + off]; r2[t] += r2[t + off]; }
        __syncthreads();
    }
    if (t == 0) {
        float mean = r1[0] * (1.f / 65536.f);
        float var  = r2[0] * (1.f / 65536.f) - mean * mean;
        stats[bg * 2]     = mean;
        stats[bg * 2 + 1] = rsqrtf(var + GEPS);
    }
}

// ---------------- GroupNorm apply: fp32 -> bf16 xn ----------------
__global__ __launch_bounds__(256) void gn_apply_kernel(const float* __restrict__ x,
                                                       const float* __restrict__ stats,
                                                       const float* __restrict__ gsc,
                                                       const float* __restrict__ gbs,
                                                       short* __restrict__ xn) {
    int i4 = blockIdx.x * 256 + threadIdx.x;  // 0 .. 2097151 (4 elems each)
    int base = i4 * 4;
    int b = base >> 21;                        // / (SEQ*CH)
    int c = base & 511;
    int sidx = (b * 32 + (c >> 4)) * 2;
    float mean = stats[sidx], rstd = stats[sidx + 1];
    float4 xv = reinterpret_cast<const float4*>(x)[i4];
    float4 sv = *reinterpret_cast<const float4*>(gsc + c);
    float4 bv = *reinterpret_cast<const float4*>(gbs + c);
    union { short s[4]; uint2 u; } p;
    p.s[0] = bf16b((xv.x - mean) * rstd * sv.x + bv.x);
    p.s[1] = bf16b((xv.y - mean) * rstd * sv.y + bv.y);
    p.s[2] = bf16b((xv.z - mean) * rstd * sv.z + bv.z);
    p.s[3] = bf16b((xv.w - mean) * rstd * sv.w + bv.w);
    reinterpret_cast<uint2*>(xn)[i4] = p.u;
}

// ---------------- weight transpose: w[K][N] fp32 -> wT[N][K] bf16 (4 weights) ----------------
__global__ __launch_bounds__(256) void wtrans_kernel(const float* __restrict__ w0,
                                                     const float* __restrict__ w1,
                                                     const float* __restrict__ w2,
                                                     const float* __restrict__ w3,
                                                     short* __restrict__ wT) {
    const float* w = (blockIdx.z == 0) ? w0 : (blockIdx.z == 1) ? w1
                   : (blockIdx.z == 2) ? w2 : w3;
    short* out = wT + (size_t)blockIdx.z * CH * CH;
    int n0 = blockIdx.x * 32, k0 = blockIdx.y * 32;
    int tx = threadIdx.x, ty = threadIdx.y;     // (32, 8)
    __shared__ float s[32][33];
    #pragma unroll
    for (int i = 0; i < 4; ++i) {
        int kk = ty + i * 8;
        s[kk][tx] = w[(size_t)(k0 + kk) * CH + n0 + tx];
    }
    __syncthreads();
    #pragma unroll
    for (int i = 0; i < 4; ++i) {
        int nn = ty + i * 8;
        out[(size_t)(n0 + nn) * CH + k0 + tx] = bf16b(s[tx][nn]);
    }
}

// ---------------- v transpose: v[b][l][d] bf16 -> vT[b][d][l] bf16 ----------------
__global__ __launch_bounds__(256) void vtrans_kernel(const short* __restrict__ v,
                                                     short* __restrict__ vT) {
    int b = blockIdx.z;
    int l0 = blockIdx.x * 32, d0 = blockIdx.y * 32;
    int tx = threadIdx.x, ty = threadIdx.y;     // (32, 8)
    __shared__ short s[32][33];
    #pragma unroll
    for (int i = 0; i < 4; ++i) {
        int ll = ty + i * 8;
        s[ll][tx] = v[((size_t)b * SEQ + l0 + ll) * CH + d0 + tx];
    }
    __syncthreads();
    #pragma unroll
    for (int i = 0; i < 4; ++i) {
        int dd = ty + i * 8;
        vT[((size_t)b * CH + d0 + dd) * SEQ + l0 + tx] = s[tx][dd];
    }
}

// ---------------- GEMM: C[m][n] = sum_k A[m][k]*BT[n][k] + bias[n]  (M=16384,N=512,K=512)
// outb != null -> bf16 out; outf != null -> fp32 out + residual add.
__global__ __launch_bounds__(256) void gemm_bt_kernel(const short* __restrict__ A,
                                                      const short* __restrict__ BT,
                                                      const float* __restrict__ bias,
                                                      short* __restrict__ outb,
                                                      float* __restrict__ outf,
                                                      const float* __restrict__ resid) {
    __shared__ short As[128 * 64];
    __shared__ short Bs[128 * 64];
    int m0 = blockIdx.x * 128, n0 = blockIdx.y * 128;
    int t = threadIdx.x;
    int w = t >> 6, lane = t & 63;
    int wr = w >> 1, wc = w & 1;
    int l15 = lane & 15, l4 = lane >> 4;
    floatx4 acc[4][4];
    #pragma unroll
    for (int i = 0; i < 4; ++i)
        #pragma unroll
        for (int j = 0; j < 4; ++j) acc[i][j] = (floatx4){0.f, 0.f, 0.f, 0.f};

    for (int k0 = 0; k0 < 512; k0 += 64) {
        __syncthreads();
        #pragma unroll
        for (int i = 0; i < 4; ++i) {
            int c = i * 256 + t;
            int row = c >> 3, off = (c & 7) * 8;
            *reinterpret_cast<uint4*>(&As[c * 8]) =
                *reinterpret_cast<const uint4*>(&A[(size_t)(m0 + row) * 512 + k0 + off]);
            *reinterpret_cast<uint4*>(&Bs[c * 8]) =
                *reinterpret_cast<const uint4*>(&BT[(size_t)(n0 + row) * 512 + k0 + off]);
        }
        __syncthreads();
        #pragma unroll
        for (int kk = 0; kk < 64; kk += 32) {
            short8 af[4], bf[4];
            #pragma unroll
            for (int i = 0; i < 4; ++i)
                af[i] = *reinterpret_cast<const short8*>(&As[(wr * 64 + i * 16 + l15) * 64 + kk + l4 * 8]);
            #pragma unroll
            for (int j = 0; j < 4; ++j)
                bf[j] = *reinterpret_cast<const short8*>(&Bs[(wc * 64 + j * 16 + l15) * 64 + kk + l4 * 8]);
            #pragma unroll
            for (int i = 0; i < 4; ++i)
                #pragma unroll
                for (int j = 0; j < 4; ++j)
                    acc[i][j] = __builtin_amdgcn_mfma_f32_16x16x32_bf16(af[i], bf[j], acc[i][j], 0, 0, 0);
        }
    }
    // epilogue: C/D layout col=lane&15, row=(lane>>4)*4+reg
    #pragma unroll
    for (int i = 0; i < 4; ++i) {
        #pragma unroll
        for (int j = 0; j < 4; ++j) {
            #pragma unroll
            for (int r = 0; r < 4; ++r) {
                int row = m0 + wr * 64 + i * 16 + l4 * 4 + r;
                int col = n0 + wc * 64 + j * 16 + l15;
                float vv = acc[i][j][r] + bias[col];
                if (outf) outf[(size_t)row * 512 + col] = vv + resid[(size_t)row * 512 + col];
                else      outb[(size_t)row * 512 + col] = bf16b(vv);
            }
        }
    }
}

// ---------------- flash attention: q[b][l][d], k[b][s][d], vT[b][d][s] (bf16) -> attn bf16
__global__ __launch_bounds__(256) void flash_kernel(const short* __restrict__ q,
                                                    const short* __restrict__ k,
                                                    const short* __restrict__ vT,
                                                    short* __restrict__ attn) {
    // smem layout (shorts): [0..16383] K tile [32][512]; [16384..32767] Vt tile [512][32]
    // Ps alias = smem[0..2047] : [wave][16][32]  (written only after all QK reads of K tile)
    __shared__ short smem[32768];   // 64 KB
    int b = blockIdx.y;
    int q0 = blockIdx.x * 64;
    int t = threadIdx.x, w = t >> 6, lane = t & 63;
    int l15 = lane & 15, l4 = lane >> 4;
    const float scale = 0.044194173824159216f;  // 1/sqrt(512)

    // Q fragments in registers: rows w*16 + l15, all 512 k
    short8 qf[16];
    {
        const short* qrow = q + ((size_t)b * SEQ + q0 + w * 16 + l15) * 512;
        #pragma unroll
        for (int ks = 0; ks < 16; ++ks)
            qf[ks] = *reinterpret_cast<const short8*>(qrow + ks * 32 + l4 * 8);
    }

    floatx4 acc[32];
    #pragma unroll
    for (int i = 0; i < 32; ++i) acc[i] = (floatx4){0.f, 0.f, 0.f, 0.f};
    float mprev[4] = {-1e30f, -1e30f, -1e30f, -1e30f};
    float lsum[4]  = {0.f, 0.f, 0.f, 0.f};

    const short* kbase = k  + (size_t)b * SEQ * 512;
    const short* vbase = vT + (size_t)b * 512 * SEQ;

    for (int s0 = 0; s0 < SEQ; s0 += 32) {
        __syncthreads();                                   // (a) prev iter reads done
        {   // stage K tile: contiguous 32*512 shorts
            const uint4* src = reinterpret_cast<const uint4*>(kbase + (size_t)s0 * 512);
            uint4* dst = reinterpret_cast<uint4*>(smem);
            #pragma unroll
            for (int i = 0; i < 8; ++i) dst[i * 256 + t] = src[i * 256 + t];
        }
        {   // stage Vt tile: rows d=0..511, cols s0..s0+31
            uint4* dst = reinterpret_cast<uint4*>(smem + 16384);
            #pragma unroll
            for (int i = 0; i < 8; ++i) {
                int c = i * 256 + t;
                int row = c >> 2, off = (c & 3) * 8;
                dst[c] = *reinterpret_cast<const uint4*>(vbase + (size_t)row * SEQ + s0 + off);
            }
        }
        __syncthreads();                                   // (c) tiles ready

        // --- QK^T : S[16 rows][32 cols] in two 16x16 C-tiles
        floatx4 sa0 = (floatx4){0.f, 0.f, 0.f, 0.f};
        floatx4 sa1 = (floatx4){0.f, 0.f, 0.f, 0.f};
        #pragma unroll
        for (int ks = 0; ks < 16; ++ks) {
            short8 b0 = *reinterpret_cast<const short8*>(&smem[l15 * 512 + ks * 32 + l4 * 8]);
            short8 b1 = *reinterpret_cast<const short8*>(&smem[(l15 + 16) * 512 + ks * 32 + l4 * 8]);
            sa0 = __builtin_amdgcn_mfma_f32_16x16x32_bf16(qf[ks], b0, sa0, 0, 0, 0);
            sa1 = __builtin_amdgcn_mfma_f32_16x16x32_bf16(qf[ks], b1, sa1, 0, 0, 0);
        }

        // --- online softmax (row = l4*4+r, replicated over 16 lanes of group)
        float p0[4], p1[4], alpha[4];
        bool changed = false;
        #pragma unroll
        for (int r = 0; r < 4; ++r) {
            float v0 = sa0[r] * scale, v1 = sa1[r] * scale;
            float mx = fmaxf(v0, v1);
            #pragma unroll
            for (int off = 1; off < 16; off <<= 1) mx = fmaxf(mx, __shfl_xor(mx, off));
            float nm = fmaxf(mprev[r], mx);
            alpha[r] = __expf(mprev[r] - nm);
            changed |= (nm > mprev[r]);
            p0[r] = __expf(v0 - nm);
            p1[r] = __expf(v1 - nm);
            float rs = p0[r] + p1[r];
            #pragma unroll
            for (int off = 1; off < 16; off <<= 1) rs += __shfl_xor(rs, off);
            lsum[r] = lsum[r] * alpha[r] + rs;
            mprev[r] = nm;
        }
        if (__ballot(changed)) {
            #pragma unroll
            for (int i = 0; i < 32; ++i)
                #pragma unroll
                for (int r = 0; r < 4; ++r) acc[i][r] *= alpha[r];
        }

        __syncthreads();                                   // (e) all QK reads of K tile done
        // write P (C layout -> LDS [16][32]) into alias region
        short* Ps = smem + w * 512;
        #pragma unroll
        for (int r = 0; r < 4; ++r) {
            Ps[(l4 * 4 + r) * 32 + l15]      = bf16b(p0[r]);
            Ps[(l4 * 4 + r) * 32 + 16 + l15] = bf16b(p1[r]);
        }
        __syncthreads();                                   // (g) P visible

        // --- PV : A = P[16][32], B^T = Vt rows (n=d), accumulate O[16][512]
        short8 pf = *reinterpret_cast<const short8*>(Ps + l15 * 32 + l4 * 8);
        const short* Vs = smem + 16384;
        #pragma unroll
        for (int tt = 0; tt < 32; ++tt) {
            short8 vf = *reinterpret_cast<const short8*>(Vs + (tt * 16 + l15) * 32 + l4 * 8);
            acc[tt] = __builtin_amdgcn_mfma_f32_16x16x32_bf16(pf, vf, acc[tt], 0, 0, 0);
        }
    }

    // epilogue: divide by l, store bf16 (row = l4*4+r, col = tt*16+l15)
    short* obase = attn + ((size_t)b * SEQ + q0 + w * 16) * 512;
    #pragma unroll
    for (int r = 0; r < 4; ++r) {
        float inv = 1.f / lsum[r];
        #pragma unroll
        for (int tt = 0; tt < 32; ++tt)
            obase[(size_t)(l4 * 4 + r) * 512 + tt * 16 + l15] = bf16b(acc[tt][r] * inv);
    }
}

extern "C" void kernel_launch(void* const* d_in, const int* in_sizes, int n_in,
                              void* d_out, int out_size, void* d_ws, size_t ws_size,
                              hipStream_t stream) {
    const float* x   = (const float*)d_in[0];
    const float* gsc = (const float*)d_in[1];
    const float* gbs = (const float*)d_in[2];
    const float* wq  = (const float*)d_in[3];
    const float* bq  = (const float*)d_in[4];
    const float* wk  = (const float*)d_in[5];
    const float* bk  = (const float*)d_in[6];
    const float* wv  = (const float*)d_in[7];
    const float* bv  = (const float*)d_in[8];
    const float* wo  = (const float*)d_in[9];
    const float* bo  = (const float*)d_in[10];
    float* out = (float*)d_out;

    char* ws = (char*)d_ws;
    const size_t NE = (size_t)BATCH * SEQ * CH;     // 8,388,608 elems
    short* xn   = (short*)(ws);                      // bf16 [B,L,C]; reused as attn output
    short* qb   = (short*)(ws + NE * 2);
    short* kb   = (short*)(ws + NE * 4);
    short* vb   = (short*)(ws + NE * 6);
    short* vTb  = (short*)(ws + NE * 8);
    short* wT   = (short*)(ws + NE * 10);            // 4 x [512][512] bf16
    float* stats = (float*)(ws + NE * 10 + (size_t)4 * CH * CH * 2);
    short* attn = xn;                                 // xn dead after QKV GEMMs

    gn_stats_kernel<<<128, 256, 0, stream>>>(x, stats);
    gn_apply_kernel<<<(int)(NE / 1024), 256, 0, stream>>>(x, stats, gsc, gbs, xn);
    wtrans_kernel<<<dim3(16, 16, 4), dim3(32, 8), 0, stream>>>(wq, wk, wv, wo, wT);

    short* wqT = wT;
    short* wkT = wT + 262144;
    short* wvT = wT + 524288;
    short* woT = wT + 786432;

    gemm_bt_kernel<<<dim3(128, 4), 256, 0, stream>>>(xn, wqT, bq, qb, nullptr, nullptr);
    gemm_bt_kernel<<<dim3(128, 4), 256, 0, stream>>>(xn, wkT, bk, kb, nullptr, nullptr);
    gemm_bt_kernel<<<dim3(128, 4), 256, 0, stream>>>(xn, wvT, bv, vb, nullptr, nullptr);
    vtrans_kernel<<<dim3(128, 16, 4), dim3(32, 8), 0, stream>>>(vb, vTb);
    flash_kernel<<<dim3(64, 4), 256, 0, stream>>>(qb, kb, vTb, attn);
    gemm_bt_kernel<<<dim3(128, 4), 256, 0, stream>>>(attn, woT, bo, nullptr, out, x);
}

// Round 2
// 654.342 us; speedup vs baseline: 1.2235x; 1.2235x over previous
//
#include <hip/hip_runtime.h>
#include <hip/hip_bf16.h>
#include <stdint.h>

#define BATCH 4
#define SEQ   4096          // 64*64 spatial
#define CH    512
#define NGRP  32
#define GEPS  1e-6f

typedef short  short8  __attribute__((ext_vector_type(8)));
typedef float  floatx4 __attribute__((ext_vector_type(4)));

static __device__ __forceinline__ short bf16b(float f) {
    __hip_bfloat16 h = __float2bfloat16(f);
    return __builtin_bit_cast(short, h);
}
static __device__ __forceinline__ float bf2f(short s) {
    unsigned u = ((unsigned)(unsigned short)s) << 16;
    return __builtin_bit_cast(float, u);
}

// ---------------- GroupNorm: stats per (b, g) over SEQ x 16 channels ----------------
__global__ __launch_bounds__(256) void gn_stats_kernel(const float* __restrict__ x,
                                                       float* __restrict__ stats) {
    int bg = blockIdx.x;            // 0..127
    int b = bg >> 5, g = bg & 31;
    int t = threadIdx.x;
    const float* base = x + (size_t)b * SEQ * CH + g * 16;
    float s1 = 0.f, s2 = 0.f;
    #pragma unroll 4
    for (int i = 0; i < 256; ++i) {
        int idx = i * 256 + t;          // 65536 elems
        int l = idx >> 4, c = idx & 15;
        float v = base[(size_t)l * CH + c];
        s1 += v; s2 += v * v;
    }
    __shared__ float r1[256], r2[256];
    r1[t] = s1; r2[t] = s2;
    __syncthreads();
    for (int off = 128; off > 0; off >>= 1) {
        if (t < off) { r1[t] += r1[t + off]; r2[t] += r2[t + off]; }
        __syncthreads();
    }
    if (t == 0) {
        float mean = r1[0] * (1.f / 65536.f);
        float var  = r2[0] * (1.f / 65536.f) - mean * mean;
        stats[bg * 2]     = mean;
        stats[bg * 2 + 1] = rsqrtf(var + GEPS);
    }
}

// ---------------- GroupNorm apply: fp32 -> bf16 xn ----------------
__global__ __launch_bounds__(256) void gn_apply_kernel(const float* __restrict__ x,
                                                       const float* __restrict__ stats,
                                                       const float* __restrict__ gsc,
                                                       const float* __restrict__ gbs,
                                                       short* __restrict__ xn) {
    int i4 = blockIdx.x * 256 + threadIdx.x;  // 4 elems each
    int base = i4 * 4;
    int b = base >> 21;                        // / (SEQ*CH)
    int c = base & 511;
    int sidx = (b * 32 + (c >> 4)) * 2;
    float mean = stats[sidx], rstd = stats[sidx + 1];
    float4 xv = reinterpret_cast<const float4*>(x)[i4];
    float4 sv = *reinterpret_cast<const float4*>(gsc + c);
    float4 bv = *reinterpret_cast<const float4*>(gbs + c);
    union { short s[4]; uint2 u; } p;
    p.s[0] = bf16b((xv.x - mean) * rstd * sv.x + bv.x);
    p.s[1] = bf16b((xv.y - mean) * rstd * sv.y + bv.y);
    p.s[2] = bf16b((xv.z - mean) * rstd * sv.z + bv.z);
    p.s[3] = bf16b((xv.w - mean) * rstd * sv.w + bv.w);
    reinterpret_cast<uint2*>(xn)[i4] = p.u;
}

// ---------------- weight transpose: w[K][N] fp32 -> wT[N][K] bf16 (4 weights) ----------------
__global__ __launch_bounds__(256) void wtrans_kernel(const float* __restrict__ w0,
                                                     const float* __restrict__ w1,
                                                     const float* __restrict__ w2,
                                                     const float* __restrict__ w3,
                                                     short* __restrict__ wT) {
    const float* w = (blockIdx.z == 0) ? w0 : (blockIdx.z == 1) ? w1
                   : (blockIdx.z == 2) ? w2 : w3;
    short* out = wT + (size_t)blockIdx.z * CH * CH;
    int n0 = blockIdx.x * 32, k0 = blockIdx.y * 32;
    int tx = threadIdx.x, ty = threadIdx.y;     // (32, 8)
    __shared__ float s[32][33];
    #pragma unroll
    for (int i = 0; i < 4; ++i) {
        int kk = ty + i * 8;
        s[kk][tx] = w[(size_t)(k0 + kk) * CH + n0 + tx];
    }
    __syncthreads();
    #pragma unroll
    for (int i = 0; i < 4; ++i) {
        int nn = ty + i * 8;
        out[(size_t)(n0 + nn) * CH + k0 + tx] = bf16b(s[tx][nn]);
    }
}

// ---------------- v transpose: v[b][l][d] bf16 -> vT[b][d][l] bf16 ----------------
__global__ __launch_bounds__(256) void vtrans_kernel(const short* __restrict__ v,
                                                     short* __restrict__ vT) {
    int b = blockIdx.z;
    int l0 = blockIdx.x * 32, d0 = blockIdx.y * 32;
    int tx = threadIdx.x, ty = threadIdx.y;     // (32, 8)
    __shared__ short s[32][33];
    #pragma unroll
    for (int i = 0; i < 4; ++i) {
        int ll = ty + i * 8;
        s[ll][tx] = v[((size_t)b * SEQ + l0 + ll) * CH + d0 + tx];
    }
    __syncthreads();
    #pragma unroll
    for (int i = 0; i < 4; ++i) {
        int dd = ty + i * 8;
        vT[((size_t)b * CH + d0 + dd) * SEQ + l0 + tx] = s[tx][dd];
    }
}

// ---------------- GEMM: C[m][n] = sum_k A[m][k]*BT[n][k] + bias[n]  (M=16384,N=512,K=512)
// XOR-swizzled LDS (16B chunks): slot(row,j) = row*8 + (j ^ (row&7))
__global__ __launch_bounds__(256) void gemm_bt_kernel(const short* __restrict__ A,
                                                      const short* __restrict__ BT,
                                                      const float* __restrict__ bias,
                                                      short* __restrict__ outb,
                                                      float* __restrict__ outf,
                                                      const float* __restrict__ resid) {
    __shared__ short As[128 * 64];
    __shared__ short Bs[128 * 64];
    int m0 = blockIdx.x * 128, n0 = blockIdx.y * 128;
    int t = threadIdx.x;
    int w = t >> 6, lane = t & 63;
    int wr = w >> 1, wc = w & 1;
    int l15 = lane & 15, l4 = lane >> 4;
    floatx4 acc[4][4];
    #pragma unroll
    for (int i = 0; i < 4; ++i)
        #pragma unroll
        for (int j = 0; j < 4; ++j) acc[i][j] = (floatx4){0.f, 0.f, 0.f, 0.f};

    for (int k0 = 0; k0 < 512; k0 += 64) {
        __syncthreads();
        #pragma unroll
        for (int i = 0; i < 4; ++i) {
            int c = i * 256 + t;
            int row = c >> 3, j = c & 7;
            int slot = row * 8 + (j ^ (row & 7));
            *reinterpret_cast<uint4*>(&As[slot * 8]) =
                *reinterpret_cast<const uint4*>(&A[(size_t)(m0 + row) * 512 + k0 + j * 8]);
            *reinterpret_cast<uint4*>(&Bs[slot * 8]) =
                *reinterpret_cast<const uint4*>(&BT[(size_t)(n0 + row) * 512 + k0 + j * 8]);
        }
        __syncthreads();
        #pragma unroll
        for (int kk = 0; kk < 64; kk += 32) {
            short8 af[4], bf[4];
            #pragma unroll
            for (int i = 0; i < 4; ++i) {
                int row = wr * 64 + i * 16 + l15;
                int j = (kk >> 3) + l4;
                af[i] = *reinterpret_cast<const short8*>(&As[(row * 8 + (j ^ (l15 & 7))) * 8]);
            }
            #pragma unroll
            for (int j2 = 0; j2 < 4; ++j2) {
                int row = wc * 64 + j2 * 16 + l15;
                int j = (kk >> 3) + l4;
                bf[j2] = *reinterpret_cast<const short8*>(&Bs[(row * 8 + (j ^ (l15 & 7))) * 8]);
            }
            #pragma unroll
            for (int i = 0; i < 4; ++i)
                #pragma unroll
                for (int j2 = 0; j2 < 4; ++j2)
                    acc[i][j2] = __builtin_amdgcn_mfma_f32_16x16x32_bf16(af[i], bf[j2], acc[i][j2], 0, 0, 0);
        }
    }
    // epilogue: C/D layout col=lane&15, row=(lane>>4)*4+reg
    #pragma unroll
    for (int i = 0; i < 4; ++i) {
        #pragma unroll
        for (int j = 0; j < 4; ++j) {
            #pragma unroll
            for (int r = 0; r < 4; ++r) {
                int row = m0 + wr * 64 + i * 16 + l4 * 4 + r;
                int col = n0 + wc * 64 + j * 16 + l15;
                float vv = acc[i][j][r] + bias[col];
                if (outf) outf[(size_t)row * 512 + col] = vv + resid[(size_t)row * 512 + col];
                else      outb[(size_t)row * 512 + col] = bf16b(vv);
            }
        }
    }
}

// ---------------- flash attention (split-s / flash-decoding, swizzled LDS) --------
// q[b][l][d], k[b][s][d], vT[b][d][s] bf16; each block sweeps half of s and writes
// unnormalized partial O (bf16) + per-row (m, l) fp32.
__global__ __launch_bounds__(256) void flash_kernel(const short* __restrict__ q,
                                                    const short* __restrict__ k,
                                                    const short* __restrict__ vT,
                                                    short* __restrict__ Opart,
                                                    float* __restrict__ ml) {
    // smem (shorts): [0,16384) K tile 32x512 swizzled; [16384,32768) Vt tile 512x32 swizzled.
    // P alias: smem[w*512 .. w*512+512) (K rows 2w..2w+1), written after barrier (e).
    __shared__ short smem[32768];   // 64 KB
    int b = blockIdx.z;
    int part = blockIdx.y;
    int q0 = blockIdx.x * 64;
    int t = threadIdx.x, w = t >> 6, lane = t & 63;
    int l15 = lane & 15, l4 = lane >> 4;
    const float scale = 0.044194173824159216f;  // 1/sqrt(512)

    // Q fragments in registers: rows w*16 + l15, all 512 k
    short8 qf[16];
    {
        const short* qrow = q + ((size_t)b * SEQ + q0 + w * 16 + l15) * 512;
        #pragma unroll
        for (int ks = 0; ks < 16; ++ks)
            qf[ks] = *reinterpret_cast<const short8*>(qrow + ks * 32 + l4 * 8);
    }

    floatx4 acc[32];
    #pragma unroll
    for (int i = 0; i < 32; ++i) acc[i] = (floatx4){0.f, 0.f, 0.f, 0.f};
    float mprev[4] = {-1e30f, -1e30f, -1e30f, -1e30f};
    float lsum[4]  = {0.f, 0.f, 0.f, 0.f};

    const short* kbase = k  + (size_t)b * SEQ * 512;
    const short* vbase = vT + (size_t)b * 512 * SEQ;

    const int vswz = l4 ^ ((l15 >> 1) & 3);    // V read swizzle (tt-independent)
    const int kswz = l15 & 7;                  // K read swizzle mask
    const int s_begin = part * (SEQ / 2);
    const int s_end   = s_begin + (SEQ / 2);

    for (int s0 = s_begin; s0 < s_end; s0 += 32) {
        __syncthreads();                                   // prev iter LDS reads done
        {   // stage K tile, swizzled: chunk(row s, j) -> slot row*64 + (j^(row&7))
            const short* src = kbase + (size_t)s0 * 512;
            #pragma unroll
            for (int i = 0; i < 8; ++i) {
                int c = i * 256 + t;
                int row = c >> 6, j = c & 63;
                int slot = row * 64 + (j ^ (row & 7));
                *reinterpret_cast<uint4*>(&smem[slot * 8]) =
                    *reinterpret_cast<const uint4*>(src + row * 512 + j * 8);
            }
        }
        {   // stage Vt tile, swizzled: chunk(d, j) -> slot d*4 + (j^((d>>1)&3))
            #pragma unroll
            for (int i = 0; i < 8; ++i) {
                int c = i * 256 + t;
                int d = c >> 2, j = c & 3;
                int slot = d * 4 + (j ^ ((d >> 1) & 3));
                *reinterpret_cast<uint4*>(&smem[16384 + slot * 8]) =
                    *reinterpret_cast<const uint4*>(vbase + (size_t)d * SEQ + s0 + j * 8);
            }
        }
        __syncthreads();                                   // tiles ready

        // --- QK^T : S[16 rows][32 cols] in two 16x16 C-tiles
        floatx4 sa0 = (floatx4){0.f, 0.f, 0.f, 0.f};
        floatx4 sa1 = (floatx4){0.f, 0.f, 0.f, 0.f};
        #pragma unroll
        for (int ks = 0; ks < 16; ++ks) {
            int js = (ks * 4 + l4) ^ kswz;
            short8 b0 = *reinterpret_cast<const short8*>(&smem[(l15 * 64 + js) * 8]);
            short8 b1 = *reinterpret_cast<const short8*>(&smem[((l15 + 16) * 64 + js) * 8]);
            sa0 = __builtin_amdgcn_mfma_f32_16x16x32_bf16(qf[ks], b0, sa0, 0, 0, 0);
            sa1 = __builtin_amdgcn_mfma_f32_16x16x32_bf16(qf[ks], b1, sa1, 0, 0, 0);
        }

        // --- online softmax (row = l4*4+r, replicated over 16 lanes of group)
        float p0[4], p1[4], alpha[4];
        bool changed = false;
        #pragma unroll
        for (int r = 0; r < 4; ++r) {
            float v0 = sa0[r] * scale, v1 = sa1[r] * scale;
            float mx = fmaxf(v0, v1);
            #pragma unroll
            for (int off = 1; off < 16; off <<= 1) mx = fmaxf(mx, __shfl_xor(mx, off));
            float nm = fmaxf(mprev[r], mx);
            alpha[r] = __expf(mprev[r] - nm);
            changed |= (nm > mprev[r]);
            p0[r] = __expf(v0 - nm);
            p1[r] = __expf(v1 - nm);
            float rs = p0[r] + p1[r];
            #pragma unroll
            for (int off = 1; off < 16; off <<= 1) rs += __shfl_xor(rs, off);
            lsum[r] = lsum[r] * alpha[r] + rs;
            mprev[r] = nm;
        }
        if (__ballot(changed)) {
            #pragma unroll
            for (int i = 0; i < 32; ++i)
                #pragma unroll
                for (int r = 0; r < 4; ++r) acc[i][r] *= alpha[r];
        }

        __syncthreads();                      // (e) all QK reads of K tile done
        // write P (C layout -> LDS [16][32]) into wave-private alias region.
        // Read back by the SAME wave only -> no barrier needed after the write.
        short* Ps = smem + w * 512;
        #pragma unroll
        for (int r = 0; r < 4; ++r) {
            Ps[(l4 * 4 + r) * 32 + l15]      = bf16b(p0[r]);
            Ps[(l4 * 4 + r) * 32 + 16 + l15] = bf16b(p1[r]);
        }

        // --- PV : A = P[16][32], B^T = Vt rows (n=d), accumulate O[16][512]
        short8 pf = *reinterpret_cast<const short8*>(Ps + l15 * 32 + l4 * 8);
        #pragma unroll
        for (int tt = 0; tt < 32; ++tt) {
            int d = tt * 16 + l15;
            short8 vf = *reinterpret_cast<const short8*>(&smem[16384 + (d * 4 + vswz) * 8]);
            acc[tt] = __builtin_amdgcn_mfma_f32_16x16x32_bf16(pf, vf, acc[tt], 0, 0, 0);
        }
    }

    // epilogue: store UNNORMALIZED partial O (bf16) + (m,l)
    short* obase = Opart + (((size_t)part * BATCH + b) * SEQ + q0 + w * 16) * 512;
    #pragma unroll
    for (int r = 0; r < 4; ++r) {
        #pragma unroll
        for (int tt = 0; tt < 32; ++tt)
            obase[(size_t)(l4 * 4 + r) * 512 + tt * 16 + l15] = bf16b(acc[tt][r]);
    }
    if (l15 == 0) {
        #pragma unroll
        for (int r = 0; r < 4; ++r) {
            size_t rowg = ((size_t)part * BATCH + b) * SEQ + q0 + w * 16 + l4 * 4 + r;
            ml[rowg * 2]     = mprev[r];
            ml[rowg * 2 + 1] = lsum[r];
        }
    }
}

// ---------------- combine the two s-partials -> normalized attn bf16 ----------------
__global__ __launch_bounds__(256) void combine_kernel(const short* __restrict__ Opart,
                                                      const float* __restrict__ ml,
                                                      short* __restrict__ attn) {
    int i8 = blockIdx.x * 256 + threadIdx.x;       // 8 bf16 per thread
    size_t row = (size_t)i8 >> 6;                  // b*SEQ + l
    float m0 = ml[row * 2], l0 = ml[row * 2 + 1];
    float m1 = ml[((size_t)BATCH * SEQ + row) * 2], l1 = ml[((size_t)BATCH * SEQ + row) * 2 + 1];
    float m = fmaxf(m0, m1);
    float e0 = __expf(m0 - m), e1 = __expf(m1 - m);
    float inv = 1.f / (e0 * l0 + e1 * l1);
    e0 *= inv; e1 *= inv;
    union { uint4 u; short s[8]; } a, bb, o;
    a.u  = reinterpret_cast<const uint4*>(Opart)[i8];
    bb.u = reinterpret_cast<const uint4*>(Opart)[(size_t)BATCH * SEQ * 512 / 8 + i8];
    #pragma unroll
    for (int e = 0; e < 8; ++e)
        o.s[e] = bf16b(bf2f(a.s[e]) * e0 + bf2f(bb.s[e]) * e1);
    reinterpret_cast<uint4*>(attn)[i8] = o.u;
}

extern "C" void kernel_launch(void* const* d_in, const int* in_sizes, int n_in,
                              void* d_out, int out_size, void* d_ws, size_t ws_size,
                              hipStream_t stream) {
    const float* x   = (const float*)d_in[0];
    const float* gsc = (const float*)d_in[1];
    const float* gbs = (const float*)d_in[2];
    const float* wq  = (const float*)d_in[3];
    const float* bq  = (const float*)d_in[4];
    const float* wk  = (const float*)d_in[5];
    const float* bk  = (const float*)d_in[6];
    const float* wv  = (const float*)d_in[7];
    const float* bv  = (const float*)d_in[8];
    const float* wo  = (const float*)d_in[9];
    const float* bo  = (const float*)d_in[10];
    float* out = (float*)d_out;

    char* ws = (char*)d_ws;
    const size_t MB = 1ull << 20;
    short* xn    = (short*)ws;                    // 16MB; reused as attn (combine output)
    short* qb    = (short*)(ws + 16 * MB);
    short* kb    = (short*)(ws + 32 * MB);
    short* vTb   = (short*)(ws + 48 * MB);
    short* wT    = (short*)(ws + 64 * MB);        // 2MB: 4 x [512][512] bf16
    float* stats = (float*)(ws + 66 * MB);        // 1KB
    float* ml    = (float*)(ws + 66 * MB + 65536);// 256KB
    short* vb    = (short*)(ws + 67 * MB);        // 16MB, dead after vtrans
    short* Opart = (short*)(ws + 67 * MB);        // 32MB, overlaps vb (vb dead by then)
    short* attn  = xn;

    gn_stats_kernel<<<128, 256, 0, stream>>>(x, stats);
    gn_apply_kernel<<<8192, 256, 0, stream>>>(x, stats, gsc, gbs, xn);
    wtrans_kernel<<<dim3(16, 16, 4), dim3(32, 8), 0, stream>>>(wq, wk, wv, wo, wT);

    short* wqT = wT;
    short* wkT = wT + 262144;
    short* wvT = wT + 524288;
    short* woT = wT + 786432;

    gemm_bt_kernel<<<dim3(128, 4), 256, 0, stream>>>(xn, wqT, bq, qb, nullptr, nullptr);
    gemm_bt_kernel<<<dim3(128, 4), 256, 0, stream>>>(xn, wkT, bk, kb, nullptr, nullptr);
    gemm_bt_kernel<<<dim3(128, 4), 256, 0, stream>>>(xn, wvT, bv, vb, nullptr, nullptr);
    vtrans_kernel<<<dim3(128, 16, 4), dim3(32, 8), 0, stream>>>(vb, vTb);
    flash_kernel<<<dim3(64, 2, 4), 256, 0, stream>>>(qb, kb, vTb, Opart, ml);
    combine_kernel<<<4096, 256, 0, stream>>>(Opart, ml, attn);
    gemm_bt_kernel<<<dim3(128, 4), 256, 0, stream>>>(attn, woT, bo, nullptr, out, x);
}

// Round 3
// 566.239 us; speedup vs baseline: 1.4139x; 1.1556x over previous
//
#include <hip/hip_runtime.h>
#include <hip/hip_bf16.h>
#include <stdint.h>

#define BATCH 4
#define SEQ   4096          // 64*64 spatial
#define CH    512
#define NGRP  32
#define GEPS  1e-6f

typedef short  short8  __attribute__((ext_vector_type(8)));
typedef float  floatx4 __attribute__((ext_vector_type(4)));

static __device__ __forceinline__ short bf16b(float f) {
    __hip_bfloat16 h = __float2bfloat16(f);
    return __builtin_bit_cast(short, h);
}
static __device__ __forceinline__ float bf2f(short s) {
    unsigned u = ((unsigned)(unsigned short)s) << 16;
    return __builtin_bit_cast(float, u);
}

// async global->LDS, 16B per lane. LDS dest = wave-uniform base + lane*16.
static __device__ __forceinline__ void dma16(const void* g, void* l) {
    __builtin_amdgcn_global_load_lds(
        (const __attribute__((address_space(1))) unsigned int*)g,
        (__attribute__((address_space(3))) unsigned int*)l, 16, 0, 0);
}

// max-reduce across the 16 lanes of a DPP row, pure VALU (no LDS traffic)
static __device__ __forceinline__ float rowmax16(float x) {
    int xi = __builtin_bit_cast(int, x);
    x = fmaxf(x, __builtin_bit_cast(float, __builtin_amdgcn_update_dpp(xi, xi, 0x128, 0xf, 0xf, true))); // row_ror:8
    xi = __builtin_bit_cast(int, x);
    x = fmaxf(x, __builtin_bit_cast(float, __builtin_amdgcn_update_dpp(xi, xi, 0x124, 0xf, 0xf, true))); // row_ror:4
    xi = __builtin_bit_cast(int, x);
    x = fmaxf(x, __builtin_bit_cast(float, __builtin_amdgcn_update_dpp(xi, xi, 0x122, 0xf, 0xf, true))); // row_ror:2
    xi = __builtin_bit_cast(int, x);
    x = fmaxf(x, __builtin_bit_cast(float, __builtin_amdgcn_update_dpp(xi, xi, 0x121, 0xf, 0xf, true))); // row_ror:1
    return x;
}

// ---------------- GroupNorm partial sums: coalesced, 256 blocks, fp32 atomics ----------------
// block covers 64 consecutive rows (all 512 ch). statsraw[bg*2] += sum, [bg*2+1] += sumsq.
__global__ __launch_bounds__(256) void gn_partial_kernel(const float* __restrict__ x,
                                                         float* __restrict__ statsraw) {
    int blk = blockIdx.x;                 // 0..255
    int t = threadIdx.x;
    size_t row0 = (size_t)blk * 64;       // within B*L rows
    int qd = t & 127;                     // column-quad: channels qd*4..qd*4+3 (one group)
    int rh = t >> 7;                      // 0/1
    const float* base = x + row0 * 512 + qd * 4;
    float s1 = 0.f, s2 = 0.f;
    #pragma unroll 4
    for (int i = 0; i < 32; ++i) {
        int r = rh + i * 2;
        float4 v = *reinterpret_cast<const float4*>(base + (size_t)r * 512);
        s1 += v.x + v.y + v.z + v.w;
        s2 += v.x * v.x + v.y * v.y + v.z * v.z + v.w * v.w;
    }
    __shared__ float a1[256], a2[256];
    a1[t] = s1; a2[t] = s2;
    __syncthreads();
    if (t < 32) {                          // one thread per group
        float u1 = 0.f, u2 = 0.f;
        #pragma unroll
        for (int e = 0; e < 4; ++e) {
            u1 += a1[t * 4 + e] + a1[128 + t * 4 + e];
            u2 += a2[t * 4 + e] + a2[128 + t * 4 + e];
        }
        int b = (int)(row0 >> 12);         // 4096 rows per batch
        atomicAdd(&statsraw[(b * 32 + t) * 2],     u1);
        atomicAdd(&statsraw[(b * 32 + t) * 2 + 1], u2);
    }
}

// ---------------- GroupNorm apply: fp32 -> bf16 xn (finalize stats inline) ----------------
__global__ __launch_bounds__(256) void gn_apply_kernel(const float* __restrict__ x,
                                                       const float* __restrict__ statsraw,
                                                       const float* __restrict__ gsc,
                                                       const float* __restrict__ gbs,
                                                       short* __restrict__ xn) {
    int i4 = blockIdx.x * 256 + threadIdx.x;  // 4 elems each
    int base = i4 * 4;
    int b = base >> 21;                        // / (SEQ*CH)
    int c = base & 511;
    int sidx = (b * 32 + (c >> 4)) * 2;
    float s1 = statsraw[sidx], s2 = statsraw[sidx + 1];
    float mean = s1 * (1.f / 65536.f);
    float var  = s2 * (1.f / 65536.f) - mean * mean;
    float rstd = rsqrtf(var + GEPS);
    float4 xv = reinterpret_cast<const float4*>(x)[i4];
    float4 sv = *reinterpret_cast<const float4*>(gsc + c);
    float4 bv = *reinterpret_cast<const float4*>(gbs + c);
    union { short s[4]; uint2 u; } p;
    p.s[0] = bf16b((xv.x - mean) * rstd * sv.x + bv.x);
    p.s[1] = bf16b((xv.y - mean) * rstd * sv.y + bv.y);
    p.s[2] = bf16b((xv.z - mean) * rstd * sv.z + bv.z);
    p.s[3] = bf16b((xv.w - mean) * rstd * sv.w + bv.w);
    reinterpret_cast<uint2*>(xn)[i4] = p.u;
}

// ---------------- weight transpose: w[K][N] fp32 -> wT[N][K] bf16 (4 weights) ----------------
__global__ __launch_bounds__(256) void wtrans_kernel(const float* __restrict__ w0,
                                                     const float* __restrict__ w1,
                                                     const float* __restrict__ w2,
                                                     const float* __restrict__ w3,
                                                     short* __restrict__ wT) {
    const float* w = (blockIdx.z == 0) ? w0 : (blockIdx.z == 1) ? w1
                   : (blockIdx.z == 2) ? w2 : w3;
    short* out = wT + (size_t)blockIdx.z * CH * CH;
    int n0 = blockIdx.x * 32, k0 = blockIdx.y * 32;
    int tx = threadIdx.x, ty = threadIdx.y;     // (32, 8)
    __shared__ float s[32][33];
    #pragma unroll
    for (int i = 0; i < 4; ++i) {
        int kk = ty + i * 8;
        s[kk][tx] = w[(size_t)(k0 + kk) * CH + n0 + tx];
    }
    __syncthreads();
    #pragma unroll
    for (int i = 0; i < 4; ++i) {
        int nn = ty + i * 8;
        out[(size_t)(n0 + nn) * CH + k0 + tx] = bf16b(s[tx][nn]);
    }
}

// ---------------- v transpose: v[b][l][d] bf16 -> vT[b][d][l] bf16 ----------------
__global__ __launch_bounds__(256) void vtrans_kernel(const short* __restrict__ v,
                                                     short* __restrict__ vT) {
    int b = blockIdx.z;
    int l0 = blockIdx.x * 32, d0 = blockIdx.y * 32;
    int tx = threadIdx.x, ty = threadIdx.y;     // (32, 8)
    __shared__ short s[32][33];
    #pragma unroll
    for (int i = 0; i < 4; ++i) {
        int ll = ty + i * 8;
        s[ll][tx] = v[((size_t)b * SEQ + l0 + ll) * CH + d0 + tx];
    }
    __syncthreads();
    #pragma unroll
    for (int i = 0; i < 4; ++i) {
        int dd = ty + i * 8;
        vT[((size_t)b * CH + d0 + dd) * SEQ + l0 + tx] = s[tx][dd];
    }
}

// ---------------- GEMM: C[m][n] = sum_k A[m][k]*BT[n][k] + bias[n]  (M=16384,N=512,K=512)
// XOR-swizzled LDS, staged via global_load_lds (inverse swizzle on global address).
__global__ __launch_bounds__(256) void gemm_bt_kernel(const short* __restrict__ A,
                                                      const short* __restrict__ BT,
                                                      const float* __restrict__ bias,
                                                      short* __restrict__ outb,
                                                      float* __restrict__ outf,
                                                      const float* __restrict__ resid) {
    __shared__ short As[128 * 64];
    __shared__ short Bs[128 * 64];
    int m0 = blockIdx.x * 128, n0 = blockIdx.y * 128;
    int t = threadIdx.x;
    int w = t >> 6, lane = t & 63;
    int wr = w >> 1, wc = w & 1;
    int l15 = lane & 15, l4 = lane >> 4;
    floatx4 acc[4][4];
    #pragma unroll
    for (int i = 0; i < 4; ++i)
        #pragma unroll
        for (int j = 0; j < 4; ++j) acc[i][j] = (floatx4){0.f, 0.f, 0.f, 0.f};

    for (int k0 = 0; k0 < 512; k0 += 64) {
        __syncthreads();
        #pragma unroll
        for (int i = 0; i < 4; ++i) {
            int c = i * 256 + t;
            int row = c >> 3, j = (c & 7) ^ (row & 7);   // inverse swizzle on source
            dma16(&A[(size_t)(m0 + row) * 512 + k0 + j * 8], &As[(c & ~63) * 8]);
            dma16(&BT[(size_t)(n0 + row) * 512 + k0 + j * 8], &Bs[(c & ~63) * 8]);
        }
        __syncthreads();   // drains vmcnt(0) -> tiles ready
        #pragma unroll
        for (int kk = 0; kk < 64; kk += 32) {
            short8 af[4], bf[4];
            #pragma unroll
            for (int i = 0; i < 4; ++i) {
                int row = wr * 64 + i * 16 + l15;
                int j = (kk >> 3) + l4;
                af[i] = *reinterpret_cast<const short8*>(&As[(row * 8 + (j ^ (l15 & 7))) * 8]);
            }
            #pragma unroll
            for (int j2 = 0; j2 < 4; ++j2) {
                int row = wc * 64 + j2 * 16 + l15;
                int j = (kk >> 3) + l4;
                bf[j2] = *reinterpret_cast<const short8*>(&Bs[(row * 8 + (j ^ (l15 & 7))) * 8]);
            }
            #pragma unroll
            for (int i = 0; i < 4; ++i)
                #pragma unroll
                for (int j2 = 0; j2 < 4; ++j2)
                    acc[i][j2] = __builtin_amdgcn_mfma_f32_16x16x32_bf16(af[i], bf[j2], acc[i][j2], 0, 0, 0);
        }
    }
    // epilogue: C/D layout col=lane&15, row=(lane>>4)*4+reg
    #pragma unroll
    for (int i = 0; i < 4; ++i) {
        #pragma unroll
        for (int j = 0; j < 4; ++j) {
            #pragma unroll
            for (int r = 0; r < 4; ++r) {
                int row = m0 + wr * 64 + i * 16 + l4 * 4 + r;
                int col = n0 + wc * 64 + j * 16 + l15;
                float vv = acc[i][j][r] + bias[col];
                if (outf) outf[(size_t)row * 512 + col] = vv + resid[(size_t)row * 512 + col];
                else      outb[(size_t)row * 512 + col] = bf16b(vv);
            }
        }
    }
}

// ---------------- flash attention (split-s, swizzled LDS, DMA staging) --------
// q[b][l][d], k[b][s][d], vT[b][d][s] bf16; each block sweeps half of s, writes
// unnormalized partial O (bf16) + per-row (m, l) fp32.
__global__ __launch_bounds__(256) void flash_kernel(const short* __restrict__ q,
                                                    const short* __restrict__ k,
                                                    const short* __restrict__ vT,
                                                    short* __restrict__ Opart,
                                                    float* __restrict__ ml) {
    // smem (shorts): [0,16384) K tile 32x512 swizzled; [16384,32768) Vt tile 512x32 swizzled.
    // P alias: smem[w*512 .. w*512+512), written after barrier (e).
    __shared__ short smem[32768];   // 64 KB -> 2 blocks/CU
    int b = blockIdx.z;
    int part = blockIdx.y;
    int q0 = blockIdx.x * 64;
    int t = threadIdx.x, w = t >> 6, lane = t & 63;
    int l15 = lane & 15, l4 = lane >> 4;
    const float scale = 0.044194173824159216f;  // 1/sqrt(512)

    // Q fragments in registers: rows w*16 + l15, all 512 k
    short8 qf[16];
    {
        const short* qrow = q + ((size_t)b * SEQ + q0 + w * 16 + l15) * 512;
        #pragma unroll
        for (int ks = 0; ks < 16; ++ks)
            qf[ks] = *reinterpret_cast<const short8*>(qrow + ks * 32 + l4 * 8);
    }

    floatx4 acc[32];
    #pragma unroll
    for (int i = 0; i < 32; ++i) acc[i] = (floatx4){0.f, 0.f, 0.f, 0.f};
    floatx4 lacc = (floatx4){0.f, 0.f, 0.f, 0.f};   // row sums via MFMA-with-ones
    float mprev[4] = {-1e30f, -1e30f, -1e30f, -1e30f};

    short8 ones;
    #pragma unroll
    for (int j = 0; j < 8; ++j) ones[j] = (short)0x3F80;   // bf16 1.0

    const short* kbase = k  + (size_t)b * SEQ * 512;
    const short* vbase = vT + (size_t)b * 512 * SEQ;

    const int vswz = l4 ^ ((l15 >> 1) & 3);    // V read swizzle (tt-independent)
    const int kswz = l15 & 7;                  // K read swizzle mask
    const int s_begin = part * (SEQ / 2);
    const int s_end   = s_begin + (SEQ / 2);

    for (int s0 = s_begin; s0 < s_end; s0 += 32) {
        __syncthreads();                                   // (a) prev iter LDS reads done
        {   // DMA K tile: slot c holds chunk (row=c>>6, j=(c&63)^(row&7))
            const short* ksrc = kbase + (size_t)s0 * 512;
            #pragma unroll
            for (int i = 0; i < 8; ++i) {
                int c = i * 256 + t;
                int row = c >> 6, j = (c & 63) ^ (row & 7);
                dma16(ksrc + row * 512 + j * 8, &smem[(c & ~63) * 8]);
            }
        }
        {   // DMA Vt tile: slot c holds chunk (d=c>>2, jv=(c&3)^((d>>1)&3))
            #pragma unroll
            for (int i = 0; i < 8; ++i) {
                int c = i * 256 + t;
                int d = c >> 2, jv = (c & 3) ^ ((d >> 1) & 3);
                dma16(vbase + (size_t)d * SEQ + s0 + jv * 8, &smem[16384 + (c & ~63) * 8]);
            }
        }
        __syncthreads();                                   // (c) vmcnt(0) drain: tiles ready

        // --- QK^T : S[16 rows][32 cols] in two 16x16 C-tiles
        floatx4 sa0 = (floatx4){0.f, 0.f, 0.f, 0.f};
        floatx4 sa1 = (floatx4){0.f, 0.f, 0.f, 0.f};
        #pragma unroll
        for (int ks = 0; ks < 16; ++ks) {
            int js = (ks * 4 + l4) ^ kswz;
            short8 b0 = *reinterpret_cast<const short8*>(&smem[(l15 * 64 + js) * 8]);
            short8 b1 = *reinterpret_cast<const short8*>(&smem[((l15 + 16) * 64 + js) * 8]);
            sa0 = __builtin_amdgcn_mfma_f32_16x16x32_bf16(qf[ks], b0, sa0, 0, 0, 0);
            sa1 = __builtin_amdgcn_mfma_f32_16x16x32_bf16(qf[ks], b1, sa1, 0, 0, 0);
        }

        // --- online softmax: max via DPP (no LDS), sums via MFMA-with-ones later
        float p0[4], p1[4], alpha[4];
        bool changed = false;
        #pragma unroll
        for (int r = 0; r < 4; ++r) {
            float v0 = sa0[r] * scale, v1 = sa1[r] * scale;
            float mx = rowmax16(fmaxf(v0, v1));
            float nm = fmaxf(mprev[r], mx);
            alpha[r] = __expf(mprev[r] - nm);
            changed |= (nm > mprev[r]);
            p0[r] = __expf(v0 - nm);
            p1[r] = __expf(v1 - nm);
            mprev[r] = nm;
        }
        if (__ballot(changed)) {
            #pragma unroll
            for (int i = 0; i < 32; ++i)
                #pragma unroll
                for (int r = 0; r < 4; ++r) acc[i][r] *= alpha[r];
            #pragma unroll
            for (int r = 0; r < 4; ++r) lacc[r] *= alpha[r];
        }

        __syncthreads();                      // (e) all QK reads of K tile done
        // write P (C layout -> LDS [16][32]) into wave-private alias region.
        short* Ps = smem + w * 512;
        #pragma unroll
        for (int r = 0; r < 4; ++r) {
            Ps[(l4 * 4 + r) * 32 + l15]      = bf16b(p0[r]);
            Ps[(l4 * 4 + r) * 32 + 16 + l15] = bf16b(p1[r]);
        }

        // --- PV : A = P[16][32], B^T = Vt rows (n=d), accumulate O[16][512]
        short8 pf = *reinterpret_cast<const short8*>(Ps + l15 * 32 + l4 * 8);
        lacc = __builtin_amdgcn_mfma_f32_16x16x32_bf16(pf, ones, lacc, 0, 0, 0);  // row sums
        #pragma unroll
        for (int tt = 0; tt < 32; ++tt) {
            int d = tt * 16 + l15;
            short8 vf = *reinterpret_cast<const short8*>(&smem[16384 + (d * 4 + vswz) * 8]);
            acc[tt] = __builtin_amdgcn_mfma_f32_16x16x32_bf16(pf, vf, acc[tt], 0, 0, 0);
        }
    }

    // epilogue: store UNNORMALIZED partial O (bf16) + (m,l)
    short* obase = Opart + (((size_t)part * BATCH + b) * SEQ + q0 + w * 16) * 512;
    #pragma unroll
    for (int r = 0; r < 4; ++r) {
        #pragma unroll
        for (int tt = 0; tt < 32; ++tt)
            obase[(size_t)(l4 * 4 + r) * 512 + tt * 16 + l15] = bf16b(acc[tt][r]);
    }
    if (l15 == 0) {
        #pragma unroll
        for (int r = 0; r < 4; ++r) {
            size_t rowg = ((size_t)part * BATCH + b) * SEQ + q0 + w * 16 + l4 * 4 + r;
            ml[rowg * 2]     = mprev[r];
            ml[rowg * 2 + 1] = lacc[r];
        }
    }
}

// ---------------- combine the two s-partials -> normalized attn bf16 ----------------
__global__ __launch_bounds__(256) void combine_kernel(const short* __restrict__ Opart,
                                                      const float* __restrict__ ml,
                                                      short* __restrict__ attn) {
    int i8 = blockIdx.x * 256 + threadIdx.x;       // 8 bf16 per thread
    size_t row = (size_t)i8 >> 6;                  // b*SEQ + l
    float m0 = ml[row * 2], l0 = ml[row * 2 + 1];
    float m1 = ml[((size_t)BATCH * SEQ + row) * 2], l1 = ml[((size_t)BATCH * SEQ + row) * 2 + 1];
    float m = fmaxf(m0, m1);
    float e0 = __expf(m0 - m), e1 = __expf(m1 - m);
    float inv = 1.f / (e0 * l0 + e1 * l1);
    e0 *= inv; e1 *= inv;
    union { uint4 u; short s[8]; } a, bb, o;
    a.u  = reinterpret_cast<const uint4*>(Opart)[i8];
    bb.u = reinterpret_cast<const uint4*>(Opart)[(size_t)BATCH * SEQ * 512 / 8 + i8];
    #pragma unroll
    for (int e = 0; e < 8; ++e)
        o.s[e] = bf16b(bf2f(a.s[e]) * e0 + bf2f(bb.s[e]) * e1);
    reinterpret_cast<uint4*>(attn)[i8] = o.u;
}

extern "C" void kernel_launch(void* const* d_in, const int* in_sizes, int n_in,
                              void* d_out, int out_size, void* d_ws, size_t ws_size,
                              hipStream_t stream) {
    const float* x   = (const float*)d_in[0];
    const float* gsc = (const float*)d_in[1];
    const float* gbs = (const float*)d_in[2];
    const float* wq  = (const float*)d_in[3];
    const float* bq  = (const float*)d_in[4];
    const float* wk  = (const float*)d_in[5];
    const float* bk  = (const float*)d_in[6];
    const float* wv  = (const float*)d_in[7];
    const float* bv  = (const float*)d_in[8];
    const float* wo  = (const float*)d_in[9];
    const float* bo  = (const float*)d_in[10];
    float* out = (float*)d_out;

    char* ws = (char*)d_ws;
    const size_t MB = 1ull << 20;
    short* xn    = (short*)ws;                    // 16MB; reused as attn (combine output)
    short* qb    = (short*)(ws + 16 * MB);
    short* kb    = (short*)(ws + 32 * MB);
    short* vTb   = (short*)(ws + 48 * MB);
    short* wT    = (short*)(ws + 64 * MB);        // 2MB: 4 x [512][512] bf16
    float* stats = (float*)(ws + 66 * MB);        // raw sums, 256 floats
    float* ml    = (float*)(ws + 66 * MB + 65536);// 256KB
    short* vb    = (short*)(ws + 67 * MB);        // 16MB, dead after vtrans
    short* Opart = (short*)(ws + 67 * MB);        // 32MB, overlaps vb (vb dead by then)
    short* attn  = xn;

    hipMemsetAsync(stats, 0, 256 * sizeof(float), stream);
    gn_partial_kernel<<<256, 256, 0, stream>>>(x, stats);
    gn_apply_kernel<<<8192, 256, 0, stream>>>(x, stats, gsc, gbs, xn);
    wtrans_kernel<<<dim3(16, 16, 4), dim3(32, 8), 0, stream>>>(wq, wk, wv, wo, wT);

    short* wqT = wT;
    short* wkT = wT + 262144;
    short* wvT = wT + 524288;
    short* woT = wT + 786432;

    gemm_bt_kernel<<<dim3(128, 4), 256, 0, stream>>>(xn, wqT, bq, qb, nullptr, nullptr);
    gemm_bt_kernel<<<dim3(128, 4), 256, 0, stream>>>(xn, wkT, bk, kb, nullptr, nullptr);
    gemm_bt_kernel<<<dim3(128, 4), 256, 0, stream>>>(xn, wvT, bv, vb, nullptr, nullptr);
    vtrans_kernel<<<dim3(128, 16, 4), dim3(32, 8), 0, stream>>>(vb, vTb);
    flash_kernel<<<dim3(64, 2, 4), 256, 0, stream>>>(qb, kb, vTb, Opart, ml);
    combine_kernel<<<4096, 256, 0, stream>>>(Opart, ml, attn);
    gemm_bt_kernel<<<dim3(128, 4), 256, 0, stream>>>(attn, woT, bo, nullptr, out, x);
}